// Round 1
// baseline (302.509 us; speedup 1.0000x reference)
//
#include <hip/hip_runtime.h>

// Conv bank of 17 fixed filters + ReLU over (128,1,32768) fp32.
// out[b,j,t] = relu( sum_k W[j,k] * x_pad[b, t+k-47] ), pad (47,48).
//
// v2 structure:
//  - Staged window xsl[j] = x[ts-48+j] (aligned base -> float4 global loads).
//  - Alternating filters j=0..11 via alternating prefix sum P (wave-shuffle
//    scan, 3 barriers total instead of 18), plane-split layout for
//    conflict-free stride-4B reads.
//  - Bump filters j=12..16 factorized: w_K = [-B | 2B | -B], B = [L|R] of
//    length K/2.  Z = B*x is computed cooperatively ONCE into LDS (float4
//    reads/writes, lane-stride 16B = conflict-free), then
//    y[p] = -Z[p] + 2 Z[p+2q] - Z[p+4q].  FMAs 186->77 per output, bump LDS
//    ops 201 b32 -> ~40 b128 per thread.
//  - Halo Z values are computed by wave 3 (no scan duty) to balance phases.

#define S_LEN    32768
#define NFILT    17
#define TILE     1024
#define NTHREADS 256
#define PITCH    284      // per-plane pitch for P (need >= 278)
#define NCHUNK   139      // 8-element chunks covering P reads up to idx 1111

// Z buffer geometry (floats): per q (K=4q), size = TILE + 4q, 16B-aligned offs
constexpr int Z1_OFF  = 0;                    // q=1 : 1028
constexpr int Z2_OFF  = Z1_OFF  + TILE + 4;   // 1028, q=2 : 1032
constexpr int Z4_OFF  = Z2_OFF  + TILE + 8;   // 2060, q=4 : 1040
constexpr int Z8_OFF  = Z4_OFF  + TILE + 16;  // 3100, q=8 : 1056
constexpr int Z16_OFF = Z8_OFF  + TILE + 32;  // 4156, q=16: 1088
constexpr int ZTOT    = Z16_OFF + TILE + 64;  // 5244 floats = 21 KB

// B[i], i in [0,2Q): i<Q -> ((i+1)/Q)^2 else ((2Q-i)/Q)^2. Exact vs numpy
// fp32 linspace for power-of-2 Q (products of small ints with 2^-k exact).
template<int Qv>
__device__ __forceinline__ float bw(int i) {
    constexpr float inv = 1.0f / (float)Qv;
    const float t = (i < Qv) ? (float)(i + 1) * inv : (float)(2 * Qv - i) * inv;
    return t * t;
}

// Z(for 4 consecutive z = 4*bi+r): Zf[z] = sum_{i<2Q} B[i]*xsl[z + (49-3Q) + i]
template<int Qv>
__device__ __forceinline__ void zcalc(const float* __restrict__ xsl,
                                      float* __restrict__ Zf, int bi) {
    constexpr int OFF  = 49 - 3 * Qv;   // 46,43,37,25,1 for q=1,2,4,8,16
    constexpr int A0Q  = OFF >> 2;      // aligned float4 base
    constexpr int SH   = OFF & 3;
    constexpr int SPAN = 2 * Qv;        // length of B
    constexpr int NW   = (SH + SPAN + 3 + 3) >> 2;
    const float4* __restrict__ xs4 =
        reinterpret_cast<const float4*>(xsl) + bi + A0Q;
    float a0 = 0.f, a1 = 0.f, a2 = 0.f, a3 = 0.f;
#pragma unroll
    for (int wi = 0; wi < NW; ++wi) {
        const float4 xw = xs4[wi];                 // lane-stride 16B: no bank conflict
#pragma unroll
        for (int e = 0; e < 4; ++e) {
            const int u = 4 * wi + e - SH;         // compile-time after unroll
            const float xv = (e == 0) ? xw.x : (e == 1) ? xw.y
                           : (e == 2) ? xw.z : xw.w;
            if (u >= 0 && u < SPAN)     a0 = fmaf(bw<Qv>(u),     xv, a0);
            if (u >= 1 && u < SPAN + 1) a1 = fmaf(bw<Qv>(u - 1), xv, a1);
            if (u >= 2 && u < SPAN + 2) a2 = fmaf(bw<Qv>(u - 2), xv, a2);
            if (u >= 3 && u < SPAN + 3) a3 = fmaf(bw<Qv>(u - 3), xv, a3);
        }
    }
    reinterpret_cast<float4*>(Zf)[bi] = make_float4(a0, a1, a2, a3);
}

// y[p..p+3] = -Z[p] + 2 Z[p+2q] - Z[p+4q],  p = 4*tid
template<int Qv>
__device__ __forceinline__ float4 bump_out(const float* __restrict__ Zf, int tid) {
    const float4* __restrict__ Z4 = reinterpret_cast<const float4*>(Zf);
    const float4 za = Z4[tid];
    float4 y;
    if constexpr (Qv >= 2) {
        const float4 zb = Z4[tid + (Qv >> 1)];
        const float4 zc = Z4[tid + Qv];
        y.x = fmaf(2.f, zb.x, -(za.x + zc.x));
        y.y = fmaf(2.f, zb.y, -(za.y + zc.y));
        y.z = fmaf(2.f, zb.z, -(za.z + zc.z));
        y.w = fmaf(2.f, zb.w, -(za.w + zc.w));
    } else {                                        // q=1: offsets 2 and 4
        const float4 zb = Z4[tid + 1];
        y.x = fmaf(2.f, za.z, -(za.x + zb.x));
        y.y = fmaf(2.f, za.w, -(za.y + zb.y));
        y.z = fmaf(2.f, zb.x, -(za.z + zb.z));
        y.w = fmaf(2.f, zb.y, -(za.w + zb.w));
    }
    return y;
}

// Alternating filter K (f[even]=-1, f[odd]=+1), 4 outputs via P differences.
// j0 = 4*tid + (48-H+r);  A = (j0 odd) ? +dP : -dP,  dP = P[j0+K]-P[j0].
template<int K>
__device__ __forceinline__ float4 alt_acc(const float* __restrict__ Psp, int tid) {
    constexpr int H = (K - 1) / 2;
    float v[4];
#pragma unroll
    for (int r = 0; r < 4; ++r) {
        const int dn  = 48 - H + r;
        const int dn2 = dn + K;
        const float pa = Psp[(dn  & 3) * PITCH + tid + (dn  >> 2)];
        const float pb = Psp[(dn2 & 3) * PITCH + tid + (dn2 >> 2)];
        const float dd = pb - pa;
        v[r] = ((r + H) & 1) ? dd : -dd;
    }
    return make_float4(v[0], v[1], v[2], v[3]);
}

__global__ __launch_bounds__(NTHREADS, 4)
void conv_bank_kernel(const float* __restrict__ x, float* __restrict__ out) {
    __shared__ __align__(16) float xsl[1136];   // x[ts-48 .. ts+1075], pad 0
    __shared__ float Psp[4 * PITCH];            // alternating prefix, plane-split
    __shared__ __align__(16) float Zb[ZTOT];    // 5 Z arrays
    __shared__ float wtot[2];                   // wave scan totals

    const int tid = threadIdx.x;
    const int bx  = blockIdx.x;
    const int ts  = bx * TILE;
    const int b   = blockIdx.y;
    const float* __restrict__ xrow = x + (size_t)b * S_LEN;

    // ---- stage: xsl[j] = x[ts-48+j], j in [0,1124); zero pad/edges ----
    if (bx >= 1 && bx <= 30) {                  // interior: aligned float4 path
        const float4* __restrict__ g4 =
            reinterpret_cast<const float4*>(xrow) + ((ts - 48) >> 2);
        float4* __restrict__ s4 = reinterpret_cast<float4*>(xsl);
#pragma unroll
        for (int i = tid; i < 284; i += NTHREADS)
            s4[i] = (i < 281) ? g4[i] : make_float4(0.f, 0.f, 0.f, 0.f);
    } else {                                    // edge blocks: guarded scalar
        for (int j = tid; j < 1136; j += NTHREADS) {
            const int g = ts - 48 + j;
            xsl[j] = (j < 1124 && (unsigned)g < (unsigned)S_LEN) ? xrow[g] : 0.f;
        }
    }
    __syncthreads();                            // barrier A

    // ---- phase 1: chunk sums + wave-shuffle scan, heavy Z (q=16, q=8) ----
    float4 xa, xb;                              // kept live for P-write phase
    float csum = 0.f, incl;
    {
        const float4* __restrict__ xs4 = reinterpret_cast<const float4*>(xsl);
        if (tid < NCHUNK) {
            xa = xs4[2 * tid];
            xb = xs4[2 * tid + 1];
            csum = (xa.x - xa.y) + (xa.z - xa.w)
                 + (xb.x - xb.y) + (xb.z - xb.w);
        }
        incl = csum;
#pragma unroll
        for (int off = 1; off < 64; off <<= 1) {
            const float v = __shfl_up(incl, off, 64);
            if ((tid & 63) >= off) incl += v;
        }
        if ((tid & 63) == 63 && tid < 128) wtot[tid >> 6] = incl;
    }
    zcalc<16>(xsl, Zb + Z16_OFF, tid);
    zcalc<8 >(xsl, Zb + Z8_OFF,  tid);
    // halo Z on wave 3 (no scan duty): z = TILE + 4*j
    if (tid >= 192 && tid < 208) zcalc<16>(xsl, Zb + Z16_OFF, 256 + (tid - 192));
    if (tid >= 208 && tid < 216) zcalc<8 >(xsl, Zb + Z8_OFF,  256 + (tid - 208));
    __syncthreads();                            // barrier B

    // ---- phase 2: light Z (q=4,2,1) + P write ----
    zcalc<4>(xsl, Zb + Z4_OFF, tid);
    zcalc<2>(xsl, Zb + Z2_OFF, tid);
    zcalc<1>(xsl, Zb + Z1_OFF, tid);
    if (tid >= 216 && tid < 220) zcalc<4>(xsl, Zb + Z4_OFF, 256 + (tid - 216));
    if (tid >= 220 && tid < 222) zcalc<2>(xsl, Zb + Z2_OFF, 256 + (tid - 220));
    if (tid == 222)              zcalc<1>(xsl, Zb + Z1_OFF, 256);

    if (tid < NCHUNK) {
        float offs = (tid >= 64) ? wtot[0] : 0.f;
        if (tid >= 128) offs += wtot[1];
        float run = offs + (incl - csum);       // P[8*tid]
        float* __restrict__ Pb = Psp + 2 * tid; // writes: lane-stride 8B (free)
        Pb[0 * PITCH + 0] = run; run += xa.x;
        Pb[1 * PITCH + 0] = run; run -= xa.y;
        Pb[2 * PITCH + 0] = run; run += xa.z;
        Pb[3 * PITCH + 0] = run; run -= xa.w;
        Pb[0 * PITCH + 1] = run; run += xb.x;
        Pb[1 * PITCH + 1] = run; run -= xb.y;
        Pb[2 * PITCH + 1] = run; run += xb.z;
        Pb[3 * PITCH + 1] = run;
    }
    __syncthreads();                            // barrier C

    // ---- compute 17 outputs for 4 consecutive positions, relu, f4 store ----
    const int t0 = ts + 4 * tid;
    float* __restrict__ obase = out + (size_t)b * (NFILT * S_LEN) + t0;

    auto store_relu = [&](int j, float4 v) {
        float4 s;
        s.x = fmaxf(v.x, 0.f); s.y = fmaxf(v.y, 0.f);
        s.z = fmaxf(v.z, 0.f); s.w = fmaxf(v.w, 0.f);
        *reinterpret_cast<float4*>(obase + (size_t)j * S_LEN) = s;
    };
    auto store_pair = [&](int j, float4 a) {
        store_relu(j, a);
        store_relu(j + 6, make_float4(-a.x, -a.y, -a.z, -a.w));
    };

    store_pair(0, alt_acc<2 >(Psp, tid));
    store_pair(1, alt_acc<4 >(Psp, tid));
    store_pair(2, alt_acc<8 >(Psp, tid));
    store_pair(3, alt_acc<16>(Psp, tid));
    store_pair(4, alt_acc<32>(Psp, tid));
    store_pair(5, alt_acc<64>(Psp, tid));

    store_relu(12, bump_out<1 >(Zb + Z1_OFF,  tid));
    store_relu(13, bump_out<2 >(Zb + Z2_OFF,  tid));
    store_relu(14, bump_out<4 >(Zb + Z4_OFF,  tid));
    store_relu(15, bump_out<8 >(Zb + Z8_OFF,  tid));
    store_relu(16, bump_out<16>(Zb + Z16_OFF, tid));
}

extern "C" void kernel_launch(void* const* d_in, const int* in_sizes, int n_in,
                              void* d_out, int out_size, void* d_ws, size_t ws_size,
                              hipStream_t stream) {
    const float* x = (const float*)d_in[0];
    float* out = (float*)d_out;
    const int nbatch = in_sizes[0] / S_LEN;     // 128
    dim3 grid(S_LEN / TILE, nbatch, 1);
    conv_bank_kernel<<<grid, NTHREADS, 0, stream>>>(x, out);
}

// Round 2
// 297.765 us; speedup vs baseline: 1.0159x; 1.0159x over previous
//
#include <hip/hip_runtime.h>

// Conv bank of 17 fixed filters + ReLU over (128,1,32768) fp32.
// out[b,j,t] = relu( sum_k W[j,k] * x_pad[b, t+k-47] ), pad (47,48).
//
// v3: store-pipe duty-cycle focus.
//   Evidence: v1 (LDS-heavy, 18 barriers) == v2 (LDS-light, 3 barriers) at
//   ~115us vs a ~50us HBM floor -> not VALU/LDS/barrier-bound. All 17 f4
//   stores were confined to the final phase (~40% of block time); with
//   phase-locked blocks the store pipe idles the rest: 0.4*6.2TB/s ~= the
//   observed ~2.6 TB/s effective.  Changes:
//   (a) 8/17 outputs stored mid-kernel: K=2,4 alternating pairs + q=1,2
//       bumps direct from xsl; q=8,16 bumps from Z (ready at barrier B).
//   (b) barrier C = raw s_barrier + lgkmcnt(0)-only wait, so early stores
//       stay in flight across it (no vmcnt(0) drain).
//   (c) LDS 30 -> 21.8 KB (Z1/Z2 dropped), __launch_bounds__(256,6):
//       target 6 blocks/CU for cross-block phase decorrelation.
//   (d) nontemporal stores (output never re-read).

#define S_LEN    32768
#define NFILT    17
#define TILE     1024
#define NTHREADS 256
#define PITCH    284      // per-plane pitch for P (need >= 278)
#define NCHUNK   139      // 8-element chunks covering P reads up to idx 1111

// Z buffers (floats), 16B-aligned offsets; only q=4,8,16 staged now.
constexpr int Z4_OFF  = 0;                    // size 1040
constexpr int Z8_OFF  = Z4_OFF + TILE + 16;   // 1040, size 1056
constexpr int Z16_OFF = Z8_OFF + TILE + 32;   // 2096, size 1088
constexpr int ZTOT    = Z16_OFF + TILE + 64;  // 3184 floats = 12.7 KB

typedef float fvec4 __attribute__((ext_vector_type(4)));

// Half-bump B[i], i in [0,2Q): ((i+1)/Q)^2 rising then ((2Q-i)/Q)^2 falling.
template<int Qv>
__device__ __forceinline__ float bw(int i) {
    constexpr float inv = 1.0f / (float)Qv;
    const float t = (i < Qv) ? (float)(i + 1) * inv : (float)(2 * Qv - i) * inv;
    return t * t;
}

// Full bump weight j in [0,6Q): [-L,-R,2L,2R,-L,-R], exact vs numpy fp32.
template<int Qv>
__device__ __forceinline__ float third_w(int j) {
    constexpr float inv = 1.0f / (float)Qv;
    const int seg = j / Qv;
    const int i = j - seg * Qv;
    const float t = ((seg & 1) == 0) ? (float)(i + 1) * inv : (float)(Qv - i) * inv;
    const float v = t * t;
    return (seg == 2 || seg == 3) ? 2.0f * v : -v;
}

// Z[4*bi+r] = sum_{i<2Q} B[i]*xsl[4*bi+r + (49-3Q) + i], r=0..3
template<int Qv>
__device__ __forceinline__ void zcalc(const float* __restrict__ xsl,
                                      float* __restrict__ Zf, int bi) {
    constexpr int OFF  = 49 - 3 * Qv;   // 37,25,1 for q=4,8,16
    constexpr int A0Q  = OFF >> 2;
    constexpr int SH   = OFF & 3;
    constexpr int SPAN = 2 * Qv;
    constexpr int NW   = (SH + SPAN + 3 + 3) >> 2;
    const float4* __restrict__ xs4 =
        reinterpret_cast<const float4*>(xsl) + bi + A0Q;
    float a0 = 0.f, a1 = 0.f, a2 = 0.f, a3 = 0.f;
#pragma unroll
    for (int wi = 0; wi < NW; ++wi) {
        const float4 xw = xs4[wi];                 // lane-stride 16B: conflict-free
#pragma unroll
        for (int e = 0; e < 4; ++e) {
            const int u = 4 * wi + e - SH;         // compile-time after unroll
            const float xv = (e == 0) ? xw.x : (e == 1) ? xw.y
                           : (e == 2) ? xw.z : xw.w;
            if (u >= 0 && u < SPAN)     a0 = fmaf(bw<Qv>(u),     xv, a0);
            if (u >= 1 && u < SPAN + 1) a1 = fmaf(bw<Qv>(u - 1), xv, a1);
            if (u >= 2 && u < SPAN + 2) a2 = fmaf(bw<Qv>(u - 2), xv, a2);
            if (u >= 3 && u < SPAN + 3) a3 = fmaf(bw<Qv>(u - 3), xv, a3);
        }
    }
    reinterpret_cast<float4*>(Zf)[bi] = make_float4(a0, a1, a2, a3);
}

// y[p..p+3] = -Z[p] + 2 Z[p+2q] - Z[p+4q],  p = 4*tid   (q >= 2)
template<int Qv>
__device__ __forceinline__ float4 bump_out(const float* __restrict__ Zf, int tid) {
    const float4* __restrict__ Z4 = reinterpret_cast<const float4*>(Zf);
    const float4 za = Z4[tid];
    const float4 zb = Z4[tid + (Qv >> 1)];
    const float4 zc = Z4[tid + Qv];
    float4 y;
    y.x = fmaf(2.f, zb.x, -(za.x + zc.x));
    y.y = fmaf(2.f, zb.y, -(za.y + zc.y));
    y.z = fmaf(2.f, zb.z, -(za.z + zc.z));
    y.w = fmaf(2.f, zb.w, -(za.w + zc.w));
    return y;
}

// Direct bump for q=1,2: rolling 4 outputs, float4 LDS reads.
// out[4t+r] = sum_u third_w(u) * xsl[4t + r + (48-C) + u],  C=(6q-1)/2
template<int Qv>
__device__ __forceinline__ float4 bump_direct(const float* __restrict__ xsl, int tid) {
    constexpr int SPAN = 6 * Qv;
    constexpr int C    = (SPAN - 1) / 2;
    constexpr int OFF  = 48 - C;        // 46 (q=1), 43 (q=2)
    constexpr int A0   = OFF >> 2;
    constexpr int SH   = OFF & 3;
    constexpr int NW   = (SH + SPAN + 3 + 3) >> 2;
    const float4* __restrict__ xs4 =
        reinterpret_cast<const float4*>(xsl) + tid + A0;
    float a0 = 0.f, a1 = 0.f, a2 = 0.f, a3 = 0.f;
#pragma unroll
    for (int wi = 0; wi < NW; ++wi) {
        const float4 xw = xs4[wi];
#pragma unroll
        for (int e = 0; e < 4; ++e) {
            const int u = 4 * wi + e - SH;
            const float xv = (e == 0) ? xw.x : (e == 1) ? xw.y
                           : (e == 2) ? xw.z : xw.w;
            if (u >= 0 && u < SPAN)     a0 = fmaf(third_w<Qv>(u),     xv, a0);
            if (u >= 1 && u < SPAN + 1) a1 = fmaf(third_w<Qv>(u - 1), xv, a1);
            if (u >= 2 && u < SPAN + 2) a2 = fmaf(third_w<Qv>(u - 2), xv, a2);
            if (u >= 3 && u < SPAN + 3) a3 = fmaf(third_w<Qv>(u - 3), xv, a3);
        }
    }
    return make_float4(a0, a1, a2, a3);
}

// K=2 and K=4 alternating filters direct from xsl (no P needed).
// s[i] = xsl[4*tid + 44 + i];  K=2: out[r]=s[r+5]-s[r+4]
//                              K=4: out[r]=-s[r+3]+s[r+4]-s[r+5]+s[r+6]
__device__ __forceinline__ void alt24_direct(const float* __restrict__ xsl, int tid,
                                             float4& o2, float4& o4) {
    const float4* __restrict__ xs4 =
        reinterpret_cast<const float4*>(xsl) + tid + 11;
    const float4 wA = xs4[0], wB = xs4[1], wC = xs4[2];
    const float s3 = wA.w, s4 = wB.x, s5 = wB.y, s6 = wB.z,
                s7 = wB.w, s8 = wC.x, s9 = wC.y;
    o2.x = s5 - s4;  o2.y = s6 - s5;  o2.z = s7 - s6;  o2.w = s8 - s7;
    o4.x = (s4 - s3) + (s6 - s5);
    o4.y = (s5 - s4) + (s7 - s6);
    o4.z = (s6 - s5) + (s8 - s7);
    o4.w = (s7 - s6) + (s9 - s8);
}

// Alternating filter K via P differences (used for K=8..64).
template<int K>
__device__ __forceinline__ float4 alt_acc(const float* __restrict__ Psp, int tid) {
    constexpr int H = (K - 1) / 2;
    float v[4];
#pragma unroll
    for (int r = 0; r < 4; ++r) {
        const int dn  = 48 - H + r;
        const int dn2 = dn + K;
        const float pa = Psp[(dn  & 3) * PITCH + tid + (dn  >> 2)];
        const float pb = Psp[(dn2 & 3) * PITCH + tid + (dn2 >> 2)];
        const float dd = pb - pa;
        v[r] = ((r + H) & 1) ? dd : -dd;
    }
    return make_float4(v[0], v[1], v[2], v[3]);
}

__global__ __launch_bounds__(NTHREADS, 6)
void conv_bank_kernel(const float* __restrict__ x, float* __restrict__ out) {
    __shared__ __align__(16) float xsl[1136];   // x[ts-48 .. ts+1075], pad 0
    __shared__ float Psp[4 * PITCH];            // alternating prefix, plane-split
    __shared__ __align__(16) float Zb[ZTOT];    // Z for q=4,8,16
    __shared__ float wtot[2];                   // wave scan totals

    const int tid = threadIdx.x;
    const int bx  = blockIdx.x;
    const int ts  = bx * TILE;
    const int b   = blockIdx.y;
    const float* __restrict__ xrow = x + (size_t)b * S_LEN;

    // ---- stage: xsl[j] = x[ts-48+j], j in [0,1124); zero pad/edges ----
    if (bx >= 1 && bx <= 30) {                  // interior: aligned float4 path
        const float4* __restrict__ g4 =
            reinterpret_cast<const float4*>(xrow) + ((ts - 48) >> 2);
        float4* __restrict__ s4 = reinterpret_cast<float4*>(xsl);
#pragma unroll
        for (int i = tid; i < 284; i += NTHREADS)
            s4[i] = (i < 281) ? g4[i] : make_float4(0.f, 0.f, 0.f, 0.f);
    } else {                                    // edge blocks: guarded scalar
        for (int j = tid; j < 1136; j += NTHREADS) {
            const int g = ts - 48 + j;
            xsl[j] = (j < 1124 && (unsigned)g < (unsigned)S_LEN) ? xrow[g] : 0.f;
        }
    }
    __syncthreads();                            // barrier A

    // ---- phase 1: chunk sums + wave-shuffle scan + heavy Z (q=16, q=8) ----
    float4 xa, xb;                              // live into P-write phase
    float csum = 0.f, incl;
    {
        const float4* __restrict__ xs4 = reinterpret_cast<const float4*>(xsl);
        if (tid < NCHUNK) {
            xa = xs4[2 * tid];
            xb = xs4[2 * tid + 1];
            csum = (xa.x - xa.y) + (xa.z - xa.w)
                 + (xb.x - xb.y) + (xb.z - xb.w);
        }
        incl = csum;
#pragma unroll
        for (int off = 1; off < 64; off <<= 1) {
            const float v = __shfl_up(incl, off, 64);
            if ((tid & 63) >= off) incl += v;
        }
        if ((tid & 63) == 63 && tid < 128) wtot[tid >> 6] = incl;
    }
    zcalc<16>(xsl, Zb + Z16_OFF, tid);
    zcalc<8 >(xsl, Zb + Z8_OFF,  tid);
    if (tid >= 192 && tid < 208) zcalc<16>(xsl, Zb + Z16_OFF, 256 + (tid - 192));
    if (tid >= 208 && tid < 216) zcalc<8 >(xsl, Zb + Z8_OFF,  256 + (tid - 208));
    __syncthreads();                            // barrier B

    const int t0 = ts + 4 * tid;
    float* __restrict__ obase = out + (size_t)b * (NFILT * S_LEN) + t0;

    auto store_relu = [&](int j, float4 v) {
        fvec4 s;
        s.x = fmaxf(v.x, 0.f); s.y = fmaxf(v.y, 0.f);
        s.z = fmaxf(v.z, 0.f); s.w = fmaxf(v.w, 0.f);
        __builtin_nontemporal_store(
            s, reinterpret_cast<fvec4*>(obase + (size_t)j * S_LEN));
    };
    auto store_pair = [&](int j, float4 a) {
        store_relu(j, a);
        store_relu(j + 6, make_float4(-a.x, -a.y, -a.z, -a.w));
    };

    // ---- early outputs (8 stores), issued before the P phase completes ----
    store_relu(16, bump_out<16>(Zb + Z16_OFF, tid));
    store_relu(15, bump_out<8 >(Zb + Z8_OFF,  tid));
    store_relu(12, bump_direct<1>(xsl, tid));
    store_relu(13, bump_direct<2>(xsl, tid));
    {
        float4 a2, a4;
        alt24_direct(xsl, tid, a2, a4);
        store_pair(0, a2);
        store_pair(1, a4);
    }

    // ---- phase 2: Z (q=4) + P write ----
    zcalc<4>(xsl, Zb + Z4_OFF, tid);
    if (tid >= 216 && tid < 220) zcalc<4>(xsl, Zb + Z4_OFF, 256 + (tid - 216));

    if (tid < NCHUNK) {
        float offs = (tid >= 64) ? wtot[0] : 0.f;
        if (tid >= 128) offs += wtot[1];
        float run = offs + (incl - csum);       // P[8*tid]
        float* __restrict__ Pb = Psp + 2 * tid; // lane-stride 8B: conflict-free
        Pb[0 * PITCH + 0] = run; run += xa.x;
        Pb[1 * PITCH + 0] = run; run -= xa.y;
        Pb[2 * PITCH + 0] = run; run += xa.z;
        Pb[3 * PITCH + 0] = run; run -= xa.w;
        Pb[0 * PITCH + 1] = run; run += xb.x;
        Pb[1 * PITCH + 1] = run; run -= xb.y;
        Pb[2 * PITCH + 1] = run; run += xb.z;
        Pb[3 * PITCH + 1] = run;
    }

    // barrier C: LDS-only ordering; early global stores stay in flight
    // (no vmcnt(0) drain — counted-wait pattern).
    asm volatile("s_waitcnt lgkmcnt(0)" ::: "memory");
    __builtin_amdgcn_s_barrier();

    // ---- final phase: remaining 9 outputs ----
    store_pair(2, alt_acc<8 >(Psp, tid));
    store_pair(3, alt_acc<16>(Psp, tid));
    store_pair(4, alt_acc<32>(Psp, tid));
    store_pair(5, alt_acc<64>(Psp, tid));
    store_relu(14, bump_out<4>(Zb + Z4_OFF, tid));
}

extern "C" void kernel_launch(void* const* d_in, const int* in_sizes, int n_in,
                              void* d_out, int out_size, void* d_ws, size_t ws_size,
                              hipStream_t stream) {
    const float* x = (const float*)d_in[0];
    float* out = (float*)d_out;
    const int nbatch = in_sizes[0] / S_LEN;     // 128
    dim3 grid(S_LEN / TILE, nbatch, 1);
    conv_bank_kernel<<<grid, NTHREADS, 0, stream>>>(x, out);
}